// Round 13
// baseline (628.082 us; speedup 1.0000x reference)
//
#include <hip/hip_runtime.h>
#include <hip/hip_fp16.h>
#include <math.h>

// Problem constants (from reference)
#define N_NODES 50000
#define IN_DIM  128
#define HIDDEN  64
#define OUT_DIM 10
#define HEADS   4
#define E_RAW   800000
#define E_TOT   (E_RAW + N_NODES)   // with self-loops: 850000
#define NEG_SLOPE 0.2f

#define NB_SCAN 196    // ceil(50000/256)
#define NB_EDGE 3321   // ceil(850000/256)
#define NB_GEMH 782    // ceil(50000/64)
#define NB_NODE 12500  // 50000/4 (one wave per node)

typedef _Float16 half8 __attribute__((ext_vector_type(8)));
typedef float floatx4 __attribute__((ext_vector_type(4)));

// ---------------- edge_index dtype detection ----------------
// flag[0] == 1  =>  int32 layout (shift 0);  flag[0] == 0  =>  int64 (shift 1).
__global__ void detect_i32(const int* __restrict__ ei, int* __restrict__ flag) {
    int t = threadIdx.x;                      // single block of 256
    int idx = 2 * (t * 3100 + 17) + 1;        // odd, < 1.6M for t < 256
    if (ei[idx] != 0) atomicOr(flag, 1);
}

// ---------------- CSR build ----------------

__global__ void zero_counts(int* __restrict__ counts, int* __restrict__ flag) {
    int i = blockIdx.x * 256 + threadIdx.x;
    if (i < N_NODES) counts[i] = 0;
    if (i == 0) flag[0] = 0;
}

__global__ void count_edges(const int* __restrict__ ei, int* __restrict__ counts,
                            const int* __restrict__ flag) {
    int t = blockIdx.x * 256 + threadIdx.x;
    if (t >= E_TOT) return;
    int sh = flag[0] ? 0 : 1;                 // int32 -> 0, int64 -> 1 (low word)
    int dst = (t < E_RAW) ? ei[(E_RAW + t) << sh] : (t - E_RAW);
    atomicAdd(&counts[dst], 1);
}

__global__ void scan1(const int* __restrict__ counts, int* __restrict__ indptr,
                      int* __restrict__ bsums) {
    __shared__ int sd[256];
    int t = threadIdx.x;
    int i = blockIdx.x * 256 + t;
    int v = (i < N_NODES) ? counts[i] : 0;
    sd[t] = v;
    __syncthreads();
    for (int o = 1; o < 256; o <<= 1) {
        int x = (t >= o) ? sd[t - o] : 0;
        __syncthreads();
        sd[t] += x;
        __syncthreads();
    }
    int incl = sd[t];
    if (i < N_NODES) indptr[i] = incl - v;   // block-local exclusive
    if (t == 255) bsums[blockIdx.x] = incl;  // block total
}

__global__ void scan2(int* __restrict__ bsums) {
    __shared__ int sd[256];
    int t = threadIdx.x;
    int v = (t < NB_SCAN) ? bsums[t] : 0;
    sd[t] = v;
    __syncthreads();
    for (int o = 1; o < 256; o <<= 1) {
        int x = (t >= o) ? sd[t - o] : 0;
        __syncthreads();
        sd[t] += x;
        __syncthreads();
    }
    if (t < NB_SCAN) bsums[t] = sd[t] - v;   // exclusive block offsets
}

__global__ void scan3(int* __restrict__ indptr, const int* __restrict__ bsums,
                      int* __restrict__ cursor) {
    int i = blockIdx.x * 256 + threadIdx.x;
    if (i < N_NODES) {
        int v = indptr[i] + bsums[blockIdx.x];
        indptr[i] = v;
        cursor[i] = v;
    }
    if (i == 0) indptr[N_NODES] = E_TOT;
}

__global__ void fill_edges(const int* __restrict__ ei, int* __restrict__ cursor,
                           int* __restrict__ esrc, int* __restrict__ edst,
                           const int* __restrict__ flag) {
    int t = blockIdx.x * 256 + threadIdx.x;
    if (t >= E_TOT) return;
    int sh = flag[0] ? 0 : 1;
    int src, dst;
    if (t < E_RAW) { src = ei[t << sh]; dst = ei[(E_RAW + t) << sh]; }
    else           { src = t - E_RAW; dst = src; }
    int pos = atomicAdd(&cursor[dst], 1);
    esrc[pos] = src;
    edst[pos] = dst;
}

// ---------------- Weight prep (once, before all layers) ----------------
// Wt[c][k] = fp16 transpose of W (so MFMA B-fragments are contiguous 16 B),
// Wa[k][0..7] = f32 (W . asrc | W . adst) -- keeps the LOGIT path exact f32:
// AL = X @ Wa == einsum(h, a) by associativity.
__global__ void wt_kernel(const float* __restrict__ W0, const float* __restrict__ W1,
                          const float* __restrict__ W2, __half* __restrict__ Wt0,
                          __half* __restrict__ Wt1, __half* __restrict__ Wt2) {
    int b = blockIdx.x, t = threadIdx.x;
    int l = b >> 8, c = b & 255;
    const float* W = (l == 0) ? W0 : (l == 1) ? W1 : W2;
    __half* Wt     = (l == 0) ? Wt0 : (l == 1) ? Wt1 : Wt2;
    int K = (l == 0) ? 128 : 64;
    if (t < K) Wt[c * K + t] = __float2half(W[t * 256 + c]);
}

__global__ void wa_kernel(const float* __restrict__ W0, const float* __restrict__ W1,
                          const float* __restrict__ W2,
                          const float* __restrict__ as0, const float* __restrict__ ad0,
                          const float* __restrict__ as1, const float* __restrict__ ad1,
                          const float* __restrict__ as2, const float* __restrict__ ad2,
                          float* __restrict__ Wa0, float* __restrict__ Wa1,
                          float* __restrict__ Wa2) {
    int t = threadIdx.x;   // one thread per (layer, k): 128 + 64 + 64 = 256
    int l, k;
    if (t < 128)      { l = 0; k = t; }
    else if (t < 192) { l = 1; k = t - 128; }
    else              { l = 2; k = t - 192; }
    const float* W  = (l == 0) ? W0 : (l == 1) ? W1 : W2;
    const float* as = (l == 0) ? as0 : (l == 1) ? as1 : as2;
    const float* ad = (l == 0) ? ad0 : (l == 1) ? ad1 : ad2;
    float* Wa       = (l == 0) ? Wa0 : (l == 1) ? Wa1 : Wa2;
    for (int h = 0; h < 4; h++) {
        float ss = 0.f, dd = 0.f;
        for (int d = 0; d < 64; d++) {
            float wv = W[k * 256 + h * 64 + d];
            ss += wv * as[h * 64 + d];
            dd += wv * ad[h * 64 + d];
        }
        Wa[k * 8 + h]     = ss;
        Wa[k * 8 + 4 + h] = dd;
    }
}

// f32 -> fp16 cast (layer-0 input); nquads = nelem/4
__global__ void cast16(const float* __restrict__ X, __half* __restrict__ Y, int nquads) {
    int i = blockIdx.x * 256 + threadIdx.x;
    if (i >= nquads) return;
    float4 v = ((const float4*)X)[i];
    __half2 a = __float22half2_rn(make_float2(v.x, v.y));
    __half2 b = __float22half2_rn(make_float2(v.z, v.w));
    ((__half2*)Y)[i * 2]     = a;
    ((__half2*)Y)[i * 2 + 1] = b;
}

// ---------------- H GEMM via MFMA (fp16 in, f32 acc, fp16 out) -------------
// Block = 64 rows x 256 cols; wave w owns rows [n0+w*16, +16).
// mfma_f32_16x16x32_f16 fragments (verified layouts, guide S3):
//   A: lane(m=lane&15, quad=lane>>4) holds Xh[row=m][k=quad*8+j], j=0..7
//      -> one 16-B load from fp16 row-major Xh.
//   B: lane holds W[k=quad*8+j][col=m] = Wt[col=m][k=quad*8+j]
//      -> one 16-B load from the fp16 TRANSPOSED Wt.
//   C/D: lane holds D[row=quad*4+i][col=m], i=0..3.
// Epilogue: C/D frags -> LDS in DIM-MAJOR order (H[n][d*4+h]), then
// contiguous 16-B row stores (fixes r12's partial-line write amplification).
template <int K>
__global__ void __launch_bounds__(256) gemm_h(
    const __half* __restrict__ Xh, const __half* __restrict__ Wt,
    __half* __restrict__ H) {
    __shared__ _Float16 lds[4 * 16 * 256];   // 32 KB, 8 KB per wave
    int t = threadIdx.x;
    int w = t >> 6, lane = t & 63;
    int m = lane & 15, quad = lane >> 4;
    int n0 = blockIdx.x * 64;
    int nr = n0 + w * 16 + m;
    int nc = (nr < N_NODES) ? nr : (N_NODES - 1);   // clamp; stores guarded

    const int KC = K / 32;
    half8 afrag[KC];
#pragma unroll
    for (int kc = 0; kc < KC; kc++)
        afrag[kc] = *(const half8*)(Xh + (size_t)nc * K + kc * 32 + quad * 8);

    _Float16* myl = lds + w * (16 * 256);
#pragma unroll
    for (int ct = 0; ct < 16; ct++) {
        floatx4 acc = {0.f, 0.f, 0.f, 0.f};
#pragma unroll
        for (int kc = 0; kc < KC; kc++) {
            half8 b = *(const half8*)(Wt + (size_t)(ct * 16 + m) * K + kc * 32 + quad * 8);
            acc = __builtin_amdgcn_mfma_f32_16x16x32_f16(afrag[kc], b, acc, 0, 0, 0);
        }
        int c = ct * 16 + m;          // global col = h*64 + d
        int h = c >> 6, d = c & 63;
#pragma unroll
        for (int i = 0; i < 4; i++)
            myl[(quad * 4 + i) * 256 + d * 4 + h] = (_Float16)acc[i];
    }
    __syncthreads();
    // repack-store: row r = t>>2, quarter p = t&3 (64 halfs = 128 B each)
    int r = t >> 2, p = t & 3;
    int n2 = n0 + r;
    if (n2 < N_NODES) {
        const uint4* src = (const uint4*)(lds + (r >> 4) * (16 * 256) + (r & 15) * 256 + p * 64);
        uint4* dst = (uint4*)(H + (size_t)n2 * 256 + p * 64);
#pragma unroll
        for (int j = 0; j < 8; j++) dst[j] = src[j];
    }
}

// ---------------- Skinny exact-f32 logit GEMM: AL = X @ Wa -----------------
// One wave per node; lane = k (and k+64 for K=128); Wa staged TRANSPOSED in
// LDS (wasT[j][k]) so per-j reads are conflict-free b32.
template <int K>
__global__ void __launch_bounds__(256) al_gemm(
    const float* __restrict__ X, const float* __restrict__ Wa,
    float* __restrict__ AL) {
    __shared__ float wasT[8 * K];
    int t = threadIdx.x;
    for (int i = t; i < K * 8; i += 256) {
        int k = i >> 3, j = i & 7;
        wasT[j * K + k] = Wa[i];
    }
    __syncthreads();
    int wave = t >> 6, lane = t & 63;
    int n = blockIdx.x * 4 + wave;   // NB_NODE*4 == 50000 exactly
    float x0 = X[(size_t)n * K + lane];
    float s[8];
#pragma unroll
    for (int j = 0; j < 8; j++) s[j] = x0 * wasT[j * K + lane];
    if (K == 128) {
        float x1 = X[(size_t)n * K + 64 + lane];
#pragma unroll
        for (int j = 0; j < 8; j++) s[j] += x1 * wasT[j * K + 64 + lane];
    }
#pragma unroll
    for (int o = 1; o < 64; o <<= 1)
#pragma unroll
        for (int j = 0; j < 8; j++) s[j] += __shfl_xor(s[j], o, 64);
    if (lane == 0) {
        *(float4*)(AL + n * 8)     = make_float4(s[0], s[1], s[2], s[3]);
        *(float4*)(AL + n * 8 + 4) = make_float4(s[4], s[5], s[6], s[7]);
    }
}

// ---------------- Per-edge unnormalized attention weights ----------------
// EW[p] = exp(leaky(AL_src + AL_dst)). No max shift: logits analytically
// bounded (validated rounds 4-12); logit path is exact f32 via Wa.
__global__ void __launch_bounds__(256) edge_weights(
    const float* __restrict__ AL, const int* __restrict__ esrc,
    const int* __restrict__ edst, float4* __restrict__ EW) {
    int p = blockIdx.x * 256 + threadIdx.x;
    if (p >= E_TOT) return;
    int s = esrc[p], d = edst[p];
    const float4* AL4 = (const float4*)AL;
    float4 as = AL4[s * 2];        // src logits (4 heads)
    float4 ad = AL4[d * 2 + 1];    // dst logits (4 heads)
    float v0 = as.x + ad.x; v0 = fmaxf(v0, NEG_SLOPE * v0);
    float v1 = as.y + ad.y; v1 = fmaxf(v1, NEG_SLOPE * v1);
    float v2 = as.z + ad.z; v2 = fmaxf(v2, NEG_SLOPE * v2);
    float v3 = as.w + ad.w; v3 = fmaxf(v3, NEG_SLOPE * v3);
    EW[p] = make_float4(__expf(v0), __expf(v1), __expf(v2), __expf(v3));
}

// ---------------- Per-destination aggregation ----------------
// One wave per dst node. Per edge: one wave-uniform 16 B EW broadcast load
// + one 8 B H gather per lane + 4 FMA / 4 add. Near the L2-miss fetch floor.
// Also emits the fp16 copy of the output (next layer's MFMA input).
__global__ void __launch_bounds__(256) aggregate(
    const __half* __restrict__ H, const float4* __restrict__ EW,
    const int* __restrict__ indptr, const int* __restrict__ esrc,
    const float* __restrict__ bias, float* __restrict__ XOUT,
    __half* __restrict__ XOUT16) {
    int wave = threadIdx.x >> 6, lane = threadIdx.x & 63;
    int n = blockIdx.x * 4 + wave;   // 12500 * 4 == 50000 exactly

    int start = indptr[n], end = indptr[n + 1];
    const float2* H2 = (const float2*)H;    // 64 float2 per node row

    float d0 = 0.f, d1 = 0.f, d2 = 0.f, d3 = 0.f;
    float a0 = 0.f, a1 = 0.f, a2 = 0.f, a3 = 0.f;

#define EDGE_BODY(E, Hv)                                            \
    {                                                               \
        d0 += E.x; d1 += E.y; d2 += E.z; d3 += E.w;                 \
        float2 c01 = __half22float2(((const __half2*)&Hv)[0]);      \
        float2 c23 = __half22float2(((const __half2*)&Hv)[1]);      \
        a0 += E.x * c01.x; a1 += E.y * c01.y;                       \
        a2 += E.z * c23.x; a3 += E.w * c23.y;                       \
    }

    for (int cb = start; cb < end; cb += 64) {
        int cnt = end - cb; if (cnt > 64) cnt = 64;
        int my_s = (lane < cnt) ? esrc[cb + lane] : 0;
        for (int base = 0; base < cnt; base += 4) {
            int m = cnt - base;   // wave-uniform
            int s0 = __shfl(my_s, base, 64);
            int s1 = __shfl(my_s, base + (1 < m ? 1 : 0), 64);
            int s2 = __shfl(my_s, base + (2 < m ? 2 : 0), 64);
            int s3 = __shfl(my_s, base + (3 < m ? 3 : 0), 64);
            float4 E0 = EW[cb + base];                       // uniform -> bcast
            float4 E1 = EW[cb + base + (1 < m ? 1 : 0)];
            float4 E2 = EW[cb + base + (2 < m ? 2 : 0)];
            float4 E3 = EW[cb + base + (3 < m ? 3 : 0)];
            float2 H0 = H2[(s0 << 6) + lane];
            float2 H1 = H2[(s1 << 6) + lane];
            float2 H2v = H2[(s2 << 6) + lane];
            float2 H3 = H2[(s3 << 6) + lane];
            EDGE_BODY(E0, H0);
            if (m > 1) EDGE_BODY(E1, H1);
            if (m > 2) EDGE_BODY(E2, H2v);
            if (m > 3) EDGE_BODY(E3, H3);
        }
    }
#undef EDGE_BODY

    float r = a0 / d0 + a1 / d1 + a2 / d2 + a3 / d3;
    r = 0.25f * r + bias[lane];
    r = r > 0.f ? r : (__expf(r) - 1.f);   // ELU
    XOUT[n * 64 + lane] = r;
    XOUT16[n * 64 + lane] = __float2half(r);
}

// ---------------- Final FC ----------------
__global__ void __launch_bounds__(256) fc_kernel(
    const float* __restrict__ X, const float* __restrict__ fcW,
    const float* __restrict__ fcb, float* __restrict__ OUT) {
    __shared__ float ws[64 * 10];
    __shared__ float bs[10];
    int t = threadIdx.x;
    for (int i = t; i < 640; i += 256) ws[i] = fcW[i];   // 640 > blockDim
    if (t < 10) bs[t] = fcb[t];
    __syncthreads();
    int n = blockIdx.x * 256 + t;
    if (n >= N_NODES) return;
    float acc[10];
#pragma unroll
    for (int c = 0; c < 10; c++) acc[c] = bs[c];
    for (int d = 0; d < 64; d++) {
        float x = X[n * 64 + d];
#pragma unroll
        for (int c = 0; c < 10; c++) acc[c] += x * ws[d * 10 + c];
    }
#pragma unroll
    for (int c = 0; c < 10; c++) OUT[n * 10 + c] = acc[c];
}

// ---------------- Launch ----------------
extern "C" void kernel_launch(void* const* d_in, const int* in_sizes, int n_in,
                              void* d_out, int out_size, void* d_ws, size_t ws_size,
                              hipStream_t stream) {
    const float* x     = (const float*)d_in[0];
    const int*   ei    = (const int*)d_in[1];
    const float* W[3]    = {(const float*)d_in[2], (const float*)d_in[6], (const float*)d_in[10]};
    const float* asrc[3] = {(const float*)d_in[3], (const float*)d_in[7], (const float*)d_in[11]};
    const float* adst[3] = {(const float*)d_in[4], (const float*)d_in[8], (const float*)d_in[12]};
    const float* bias[3] = {(const float*)d_in[5], (const float*)d_in[9], (const float*)d_in[13]};
    const float* fcW = (const float*)d_in[14];
    const float* fcb = (const float*)d_in[15];
    float* out = (float*)d_out;

    char* ws = (char*)d_ws;
    size_t off = 0;
    auto alloc = [&](size_t bytes) {
        void* p = ws + off;
        off = (off + bytes + 255) & ~(size_t)255;
        return p;
    };
    __half* H     = (__half*)alloc((size_t)N_NODES * 256 * 2);  // 25.6 MB fp16
    float*  AL    = (float*)alloc((size_t)N_NODES * 8 * 4);     // 1.6 MB
    float4* EW    = (float4*)alloc((size_t)E_TOT * 16);         // 13.6 MB
    float*  XA    = (float*)alloc((size_t)N_NODES * 64 * 4);    // 12.8 MB
    float*  XB    = (float*)alloc((size_t)N_NODES * 64 * 4);    // 12.8 MB
    __half* Xh0   = (__half*)alloc((size_t)N_NODES * 128 * 2);  // 12.8 MB
    __half* XA16  = (__half*)alloc((size_t)N_NODES * 64 * 2);   // 6.4 MB
    __half* XB16  = (__half*)alloc((size_t)N_NODES * 64 * 2);   // 6.4 MB
    __half* Wt0   = (__half*)alloc(256 * 128 * 2);
    __half* Wt1   = (__half*)alloc(256 * 64 * 2);
    __half* Wt2   = (__half*)alloc(256 * 64 * 2);
    float*  Wa0   = (float*)alloc(128 * 8 * 4);
    float*  Wa1   = (float*)alloc(64 * 8 * 4);
    float*  Wa2   = (float*)alloc(64 * 8 * 4);
    int* counts = (int*)alloc((size_t)N_NODES * 4);
    int* indptr = (int*)alloc((size_t)(N_NODES + 1) * 4);
    int* cursor = (int*)alloc((size_t)N_NODES * 4);
    int* esrc   = (int*)alloc((size_t)E_TOT * 4);
    int* edst   = (int*)alloc((size_t)E_TOT * 4);
    int* bsums  = (int*)alloc(256 * 4);
    int* flag   = (int*)alloc(256 * 4);

    // CSR build (graph is identical each call; ws is re-poisoned so rebuild)
    zero_counts<<<NB_SCAN, 256, 0, stream>>>(counts, flag);
    detect_i32<<<1, 256, 0, stream>>>(ei, flag);
    count_edges<<<NB_EDGE, 256, 0, stream>>>(ei, counts, flag);
    scan1<<<NB_SCAN, 256, 0, stream>>>(counts, indptr, bsums);
    scan2<<<1, 256, 0, stream>>>(bsums);
    scan3<<<NB_SCAN, 256, 0, stream>>>(indptr, bsums, cursor);
    fill_edges<<<NB_EDGE, 256, 0, stream>>>(ei, cursor, esrc, edst, flag);

    // weight prep + input cast
    wt_kernel<<<768, 256, 0, stream>>>(W[0], W[1], W[2], Wt0, Wt1, Wt2);
    wa_kernel<<<1, 256, 0, stream>>>(W[0], W[1], W[2], asrc[0], adst[0],
                                     asrc[1], adst[1], asrc[2], adst[2],
                                     Wa0, Wa1, Wa2);
    cast16<<<6250, 256, 0, stream>>>(x, Xh0, N_NODES * 128 / 4);

    // Layer 0
    gemm_h<128><<<NB_GEMH, 256, 0, stream>>>(Xh0, Wt0, H);
    al_gemm<128><<<NB_NODE, 256, 0, stream>>>(x, Wa0, AL);
    edge_weights<<<NB_EDGE, 256, 0, stream>>>(AL, esrc, edst, EW);
    aggregate<<<NB_NODE, 256, 0, stream>>>(H, EW, indptr, esrc, bias[0], XA, XA16);
    // Layer 1
    gemm_h<64><<<NB_GEMH, 256, 0, stream>>>(XA16, Wt1, H);
    al_gemm<64><<<NB_NODE, 256, 0, stream>>>(XA, Wa1, AL);
    edge_weights<<<NB_EDGE, 256, 0, stream>>>(AL, esrc, edst, EW);
    aggregate<<<NB_NODE, 256, 0, stream>>>(H, EW, indptr, esrc, bias[1], XB, XB16);
    // Layer 2
    gemm_h<64><<<NB_GEMH, 256, 0, stream>>>(XB16, Wt2, H);
    al_gemm<64><<<NB_NODE, 256, 0, stream>>>(XB, Wa2, AL);
    edge_weights<<<NB_EDGE, 256, 0, stream>>>(AL, esrc, edst, EW);
    aggregate<<<NB_NODE, 256, 0, stream>>>(H, EW, indptr, esrc, bias[2], XA, XA16);

    // Final FC
    fc_kernel<<<NB_SCAN, 256, 0, stream>>>(XA, fcW, fcb, out);
}

// Round 14
// 574.731 us; speedup vs baseline: 1.0928x; 1.0928x over previous
//
#include <hip/hip_runtime.h>
#include <hip/hip_fp16.h>
#include <math.h>

// Problem constants (from reference)
#define N_NODES 50000
#define IN_DIM  128
#define HIDDEN  64
#define OUT_DIM 10
#define HEADS   4
#define E_RAW   800000
#define E_TOT   (E_RAW + N_NODES)   // with self-loops: 850000
#define NEG_SLOPE 0.2f

#define NB_SCAN 196    // ceil(50000/256)
#define NB_EDGE 3321   // ceil(850000/256)
#define NB_GEMH 782    // ceil(50000/64)
#define NB_NODE 12500  // 50000/4 (one wave per node)

typedef _Float16 half8 __attribute__((ext_vector_type(8)));
typedef float floatx4 __attribute__((ext_vector_type(4)));

// ---------------- edge_index dtype detection ----------------
// flag[0] == 1  =>  int32 layout (shift 0);  flag[0] == 0  =>  int64 (shift 1).
__global__ void detect_i32(const int* __restrict__ ei, int* __restrict__ flag) {
    int t = threadIdx.x;                      // single block of 256
    int idx = 2 * (t * 3100 + 17) + 1;        // odd, < 1.6M for t < 256
    if (ei[idx] != 0) atomicOr(flag, 1);
}

// ---------------- CSR build ----------------

__global__ void zero_counts(int* __restrict__ counts, int* __restrict__ flag) {
    int i = blockIdx.x * 256 + threadIdx.x;
    if (i < N_NODES) counts[i] = 0;
    if (i == 0) flag[0] = 0;
}

__global__ void count_edges(const int* __restrict__ ei, int* __restrict__ counts,
                            const int* __restrict__ flag) {
    int t = blockIdx.x * 256 + threadIdx.x;
    if (t >= E_TOT) return;
    int sh = flag[0] ? 0 : 1;                 // int32 -> 0, int64 -> 1 (low word)
    int dst = (t < E_RAW) ? ei[(E_RAW + t) << sh] : (t - E_RAW);
    atomicAdd(&counts[dst], 1);
}

__global__ void scan1(const int* __restrict__ counts, int* __restrict__ indptr,
                      int* __restrict__ bsums) {
    __shared__ int sd[256];
    int t = threadIdx.x;
    int i = blockIdx.x * 256 + t;
    int v = (i < N_NODES) ? counts[i] : 0;
    sd[t] = v;
    __syncthreads();
    for (int o = 1; o < 256; o <<= 1) {
        int x = (t >= o) ? sd[t - o] : 0;
        __syncthreads();
        sd[t] += x;
        __syncthreads();
    }
    int incl = sd[t];
    if (i < N_NODES) indptr[i] = incl - v;   // block-local exclusive
    if (t == 255) bsums[blockIdx.x] = incl;  // block total
}

__global__ void scan2(int* __restrict__ bsums) {
    __shared__ int sd[256];
    int t = threadIdx.x;
    int v = (t < NB_SCAN) ? bsums[t] : 0;
    sd[t] = v;
    __syncthreads();
    for (int o = 1; o < 256; o <<= 1) {
        int x = (t >= o) ? sd[t - o] : 0;
        __syncthreads();
        sd[t] += x;
        __syncthreads();
    }
    if (t < NB_SCAN) bsums[t] = sd[t] - v;   // exclusive block offsets
}

__global__ void scan3(int* __restrict__ indptr, const int* __restrict__ bsums,
                      int* __restrict__ cursor) {
    int i = blockIdx.x * 256 + threadIdx.x;
    if (i < N_NODES) {
        int v = indptr[i] + bsums[blockIdx.x];
        indptr[i] = v;
        cursor[i] = v;
    }
    if (i == 0) indptr[N_NODES] = E_TOT;
}

__global__ void fill_edges(const int* __restrict__ ei, int* __restrict__ cursor,
                           int* __restrict__ esrc, int* __restrict__ edst,
                           const int* __restrict__ flag) {
    int t = blockIdx.x * 256 + threadIdx.x;
    if (t >= E_TOT) return;
    int sh = flag[0] ? 0 : 1;
    int src, dst;
    if (t < E_RAW) { src = ei[t << sh]; dst = ei[(E_RAW + t) << sh]; }
    else           { src = t - E_RAW; dst = src; }
    int pos = atomicAdd(&cursor[dst], 1);
    esrc[pos] = src;
    edst[pos] = dst;
}

// ---------------- Weight prep ----------------
// Wtf = fp16 W in MFMA B-FRAGMENT ORDER: fragment f=(ct,kc,lane) holds
// 8 halfs W[k=kc*32+quad*8+j][col=ct*16+m] (m=lane&15, quad=lane>>4), stored
// contiguously -> gemm_h stages with coalesced uint4 copies and reads
// conflict-free ds_read_b128 at lane*16.
__global__ void wtf_kernel(const float* __restrict__ W0, const float* __restrict__ W1,
                           const float* __restrict__ W2, __half* __restrict__ Wtf0,
                           __half* __restrict__ Wtf1, __half* __restrict__ Wtf2) {
    int i = blockIdx.x * 256 + threadIdx.x;
    // L0: 16*4*64 = 4096 frags; L1/L2: 16*2*64 = 2048 each
    int K, f;
    const float* W; __half* Wtf;
    if (i < 4096)      { f = i;        K = 128; W = W0; Wtf = Wtf0; }
    else if (i < 6144) { f = i - 4096; K = 64;  W = W1; Wtf = Wtf1; }
    else if (i < 8192) { f = i - 6144; K = 64;  W = W2; Wtf = Wtf2; }
    else return;
    int KC = K / 32;
    int lane = f & 63, kc = (f >> 6) % KC, ct = f / (64 * KC);
    int m = lane & 15, quad = lane >> 4;
    int col = ct * 16 + m;
    __half tmp[8];
#pragma unroll
    for (int j = 0; j < 8; j++)
        tmp[j] = __float2half(W[(kc * 32 + quad * 8 + j) * 256 + col]);
    *(uint4*)(Wtf + (size_t)f * 8) = *(uint4*)tmp;
}

// Wa[k][0..7] = f32 (W·asrc | W·adst): exact-f32 logit path (AL = X @ Wa).
// One block per (layer,k); wave h handles head h: coalesced 64-float row read
// + shuffle reduce. (r13's single-block version was a ~40 us serial stall.)
__global__ void wa_kernel(const float* __restrict__ W0, const float* __restrict__ W1,
                          const float* __restrict__ W2,
                          const float* __restrict__ as0, const float* __restrict__ ad0,
                          const float* __restrict__ as1, const float* __restrict__ ad1,
                          const float* __restrict__ as2, const float* __restrict__ ad2,
                          float* __restrict__ Wa0, float* __restrict__ Wa1,
                          float* __restrict__ Wa2) {
    int b = blockIdx.x;   // 0..255: L0 k=0..127; L1 k=0..63; L2 k=0..63
    int l, k;
    if (b < 128)      { l = 0; k = b; }
    else if (b < 192) { l = 1; k = b - 128; }
    else              { l = 2; k = b - 192; }
    const float* W  = (l == 0) ? W0 : (l == 1) ? W1 : W2;
    const float* as = (l == 0) ? as0 : (l == 1) ? as1 : as2;
    const float* ad = (l == 0) ? ad0 : (l == 1) ? ad1 : ad2;
    float* Wa       = (l == 0) ? Wa0 : (l == 1) ? Wa1 : Wa2;
    int h = threadIdx.x >> 6, d = threadIdx.x & 63;
    float wv = W[k * 256 + h * 64 + d];
    float ss = wv * as[h * 64 + d];
    float dd = wv * ad[h * 64 + d];
#pragma unroll
    for (int o = 1; o < 64; o <<= 1) {
        ss += __shfl_xor(ss, o, 64);
        dd += __shfl_xor(dd, o, 64);
    }
    if (d == 0) {
        Wa[k * 8 + h]     = ss;
        Wa[k * 8 + 4 + h] = dd;
    }
}

// f32 -> fp16 cast (layer-0 input); nquads = nelem/4
__global__ void cast16(const float* __restrict__ X, __half* __restrict__ Y, int nquads) {
    int i = blockIdx.x * 256 + threadIdx.x;
    if (i >= nquads) return;
    float4 v = ((const float4*)X)[i];
    __half2 a = __float22half2_rn(make_float2(v.x, v.y));
    __half2 b = __float22half2_rn(make_float2(v.z, v.w));
    ((__half2*)Y)[i * 2]     = a;
    ((__half2*)Y)[i * 2 + 1] = b;
}

// ---------------- H GEMM via MFMA (fp16 in, f32 acc, fp16 out) -------------
// Block = 64 rows x 256 cols; wave w owns rows [n0+w*16,+16).
// W comes from LDS: Wtf staged in 8/16-ct chunks (2048 uint4 = 32 KB, fully
// coalesced), inner loop = ds_read_b128 (lane-consecutive) + MFMA — no global
// traffic in-loop (r13 loaded B from global per (ct,kc): ~60 us of exposed
// L2 latency at 3 blocks/CU). All 16 ct accs live in regs (64 VGPRs).
// Epilogue reuses the stage buffer: per-wave dim-major repack -> 16 B stores.
template <int K>
__global__ void __launch_bounds__(256) gemm_h(
    const __half* __restrict__ Xh, const __half* __restrict__ Wtf,
    __half* __restrict__ H) {
    __shared__ _Float16 lds[16384];   // 32 KB
    const int KC = K / 32;
    const int CTC = (K == 128) ? 8 : 16;   // ct's per stage chunk
    const int NCHUNK = 16 / CTC;
    int t = threadIdx.x;
    int w = t >> 6, lane = t & 63;
    int m = lane & 15, quad = lane >> 4;
    int n0 = blockIdx.x * 64;
    int nr = n0 + w * 16 + m;
    int nc = (nr < N_NODES) ? nr : (N_NODES - 1);   // clamp; stores guarded

    half8 afrag[KC];
#pragma unroll
    for (int kc = 0; kc < KC; kc++)
        afrag[kc] = *(const half8*)(Xh + (size_t)nc * K + kc * 32 + quad * 8);

    floatx4 accs[16];
    const uint4* Wg = (const uint4*)Wtf;
#pragma unroll
    for (int c = 0; c < NCHUNK; c++) {
        __syncthreads();
        // stage chunk: CTC*KC*64 fragments = 2048 uint4 (both K), 8/thread
        uint4* dstl = (uint4*)lds;
        const uint4* srcg = Wg + (size_t)c * 2048;
#pragma unroll
        for (int q = 0; q < 8; q++) dstl[t + 256 * q] = srcg[t + 256 * q];
        __syncthreads();
#pragma unroll
        for (int ctl = 0; ctl < CTC; ctl++) {
            floatx4 acc = {0.f, 0.f, 0.f, 0.f};
#pragma unroll
            for (int kc = 0; kc < KC; kc++) {
                half8 b = *(const half8*)&lds[((ctl * KC + kc) * 64 + lane) * 8];
                acc = __builtin_amdgcn_mfma_f32_16x16x32_f16(afrag[kc], b, acc, 0, 0, 0);
            }
            accs[c * CTC + ctl] = acc;
        }
    }
    __syncthreads();   // all waves done with staged W; buffer becomes epilogue
    _Float16* myl = lds + w * (16 * 256);
#pragma unroll
    for (int ct = 0; ct < 16; ct++) {
        int cc = ct * 16 + m;          // global col = h*64 + d
        int h = cc >> 6, d = cc & 63;
#pragma unroll
        for (int i = 0; i < 4; i++)
            myl[(quad * 4 + i) * 256 + d * 4 + h] = (_Float16)accs[ct][i];
    }
    __syncthreads();
    // repack-store: row r = t>>2 (wave-local region), quarter p = t&3
    int r = t >> 2, p = t & 3;
    int n2 = n0 + r;
    if (n2 < N_NODES) {
        const uint4* src = (const uint4*)(lds + (r >> 4) * (16 * 256) + (r & 15) * 256 + p * 64);
        uint4* dst = (uint4*)(H + (size_t)n2 * 256 + p * 64);
#pragma unroll
        for (int j = 0; j < 8; j++) dst[j] = src[j];
    }
}

// ---------------- Skinny exact-f32 logit GEMM: AL = X @ Wa -----------------
template <int K>
__global__ void __launch_bounds__(256) al_gemm(
    const float* __restrict__ X, const float* __restrict__ Wa,
    float* __restrict__ AL) {
    __shared__ float wasT[8 * K];
    int t = threadIdx.x;
    for (int i = t; i < K * 8; i += 256) {
        int k = i >> 3, j = i & 7;
        wasT[j * K + k] = Wa[i];
    }
    __syncthreads();
    int wave = t >> 6, lane = t & 63;
    int n = blockIdx.x * 4 + wave;   // NB_NODE*4 == 50000 exactly
    float x0 = X[(size_t)n * K + lane];
    float s[8];
#pragma unroll
    for (int j = 0; j < 8; j++) s[j] = x0 * wasT[j * K + lane];
    if (K == 128) {
        float x1 = X[(size_t)n * K + 64 + lane];
#pragma unroll
        for (int j = 0; j < 8; j++) s[j] += x1 * wasT[j * K + 64 + lane];
    }
#pragma unroll
    for (int o = 1; o < 64; o <<= 1)
#pragma unroll
        for (int j = 0; j < 8; j++) s[j] += __shfl_xor(s[j], o, 64);
    if (lane == 0) {
        *(float4*)(AL + n * 8)     = make_float4(s[0], s[1], s[2], s[3]);
        *(float4*)(AL + n * 8 + 4) = make_float4(s[4], s[5], s[6], s[7]);
    }
}

// ---------------- Per-edge unnormalized attention weights ----------------
// EW[p] = exp(leaky(AL_src + AL_dst)). No max shift: logits analytically
// bounded (validated rounds 4-13); logit path is exact f32 via Wa.
__global__ void __launch_bounds__(256) edge_weights(
    const float* __restrict__ AL, const int* __restrict__ esrc,
    const int* __restrict__ edst, float4* __restrict__ EW) {
    int p = blockIdx.x * 256 + threadIdx.x;
    if (p >= E_TOT) return;
    int s = esrc[p], d = edst[p];
    const float4* AL4 = (const float4*)AL;
    float4 as = AL4[s * 2];        // src logits (4 heads)
    float4 ad = AL4[d * 2 + 1];    // dst logits (4 heads)
    float v0 = as.x + ad.x; v0 = fmaxf(v0, NEG_SLOPE * v0);
    float v1 = as.y + ad.y; v1 = fmaxf(v1, NEG_SLOPE * v1);
    float v2 = as.z + ad.z; v2 = fmaxf(v2, NEG_SLOPE * v2);
    float v3 = as.w + ad.w; v3 = fmaxf(v3, NEG_SLOPE * v3);
    EW[p] = make_float4(__expf(v0), __expf(v1), __expf(v2), __expf(v3));
}

// ---------------- Per-destination aggregation ----------------
// One wave per dst node. Per edge: one wave-uniform 16 B EW broadcast load
// + one 8 B H gather per lane + 4 FMA / 4 add. Near the L2-miss fetch floor.
// Also emits the fp16 copy of the output (next layer's MFMA input).
__global__ void __launch_bounds__(256) aggregate(
    const __half* __restrict__ H, const float4* __restrict__ EW,
    const int* __restrict__ indptr, const int* __restrict__ esrc,
    const float* __restrict__ bias, float* __restrict__ XOUT,
    __half* __restrict__ XOUT16) {
    int wave = threadIdx.x >> 6, lane = threadIdx.x & 63;
    int n = blockIdx.x * 4 + wave;   // 12500 * 4 == 50000 exactly

    int start = indptr[n], end = indptr[n + 1];
    const float2* H2 = (const float2*)H;    // 64 float2 per node row

    float d0 = 0.f, d1 = 0.f, d2 = 0.f, d3 = 0.f;
    float a0 = 0.f, a1 = 0.f, a2 = 0.f, a3 = 0.f;

#define EDGE_BODY(E, Hv)                                            \
    {                                                               \
        d0 += E.x; d1 += E.y; d2 += E.z; d3 += E.w;                 \
        float2 c01 = __half22float2(((const __half2*)&Hv)[0]);      \
        float2 c23 = __half22float2(((const __half2*)&Hv)[1]);      \
        a0 += E.x * c01.x; a1 += E.y * c01.y;                       \
        a2 += E.z * c23.x; a3 += E.w * c23.y;                       \
    }

    for (int cb = start; cb < end; cb += 64) {
        int cnt = end - cb; if (cnt > 64) cnt = 64;
        int my_s = (lane < cnt) ? esrc[cb + lane] : 0;
        for (int base = 0; base < cnt; base += 4) {
            int m = cnt - base;   // wave-uniform
            int s0 = __shfl(my_s, base, 64);
            int s1 = __shfl(my_s, base + (1 < m ? 1 : 0), 64);
            int s2 = __shfl(my_s, base + (2 < m ? 2 : 0), 64);
            int s3 = __shfl(my_s, base + (3 < m ? 3 : 0), 64);
            float4 E0 = EW[cb + base];                       // uniform -> bcast
            float4 E1 = EW[cb + base + (1 < m ? 1 : 0)];
            float4 E2 = EW[cb + base + (2 < m ? 2 : 0)];
            float4 E3 = EW[cb + base + (3 < m ? 3 : 0)];
            float2 H0 = H2[(s0 << 6) + lane];
            float2 H1 = H2[(s1 << 6) + lane];
            float2 H2v = H2[(s2 << 6) + lane];
            float2 H3 = H2[(s3 << 6) + lane];
            EDGE_BODY(E0, H0);
            if (m > 1) EDGE_BODY(E1, H1);
            if (m > 2) EDGE_BODY(E2, H2v);
            if (m > 3) EDGE_BODY(E3, H3);
        }
    }
#undef EDGE_BODY

    float r = a0 / d0 + a1 / d1 + a2 / d2 + a3 / d3;
    r = 0.25f * r + bias[lane];
    r = r > 0.f ? r : (__expf(r) - 1.f);   // ELU
    XOUT[n * 64 + lane] = r;
    XOUT16[n * 64 + lane] = __float2half(r);
}

// ---------------- Final FC ----------------
__global__ void __launch_bounds__(256) fc_kernel(
    const float* __restrict__ X, const float* __restrict__ fcW,
    const float* __restrict__ fcb, float* __restrict__ OUT) {
    __shared__ float ws[64 * 10];
    __shared__ float bs[10];
    int t = threadIdx.x;
    for (int i = t; i < 640; i += 256) ws[i] = fcW[i];   // 640 > blockDim
    if (t < 10) bs[t] = fcb[t];
    __syncthreads();
    int n = blockIdx.x * 256 + t;
    if (n >= N_NODES) return;
    float acc[10];
#pragma unroll
    for (int c = 0; c < 10; c++) acc[c] = bs[c];
    for (int d = 0; d < 64; d++) {
        float x = X[n * 64 + d];
#pragma unroll
        for (int c = 0; c < 10; c++) acc[c] += x * ws[d * 10 + c];
    }
#pragma unroll
    for (int c = 0; c < 10; c++) OUT[n * 10 + c] = acc[c];
}

// ---------------- Launch ----------------
extern "C" void kernel_launch(void* const* d_in, const int* in_sizes, int n_in,
                              void* d_out, int out_size, void* d_ws, size_t ws_size,
                              hipStream_t stream) {
    const float* x     = (const float*)d_in[0];
    const int*   ei    = (const int*)d_in[1];
    const float* W[3]    = {(const float*)d_in[2], (const float*)d_in[6], (const float*)d_in[10]};
    const float* asrc[3] = {(const float*)d_in[3], (const float*)d_in[7], (const float*)d_in[11]};
    const float* adst[3] = {(const float*)d_in[4], (const float*)d_in[8], (const float*)d_in[12]};
    const float* bias[3] = {(const float*)d_in[5], (const float*)d_in[9], (const float*)d_in[13]};
    const float* fcW = (const float*)d_in[14];
    const float* fcb = (const float*)d_in[15];
    float* out = (float*)d_out;

    char* ws = (char*)d_ws;
    size_t off = 0;
    auto alloc = [&](size_t bytes) {
        void* p = ws + off;
        off = (off + bytes + 255) & ~(size_t)255;
        return p;
    };
    __half* H     = (__half*)alloc((size_t)N_NODES * 256 * 2);  // 25.6 MB fp16
    float*  AL    = (float*)alloc((size_t)N_NODES * 8 * 4);     // 1.6 MB
    float4* EW    = (float4*)alloc((size_t)E_TOT * 16);         // 13.6 MB
    float*  XA    = (float*)alloc((size_t)N_NODES * 64 * 4);    // 12.8 MB
    float*  XB    = (float*)alloc((size_t)N_NODES * 64 * 4);    // 12.8 MB
    __half* Xh0   = (__half*)alloc((size_t)N_NODES * 128 * 2);  // 12.8 MB
    __half* XA16  = (__half*)alloc((size_t)N_NODES * 64 * 2);   // 6.4 MB
    __half* XB16  = (__half*)alloc((size_t)N_NODES * 64 * 2);   // 6.4 MB
    __half* Wtf0  = (__half*)alloc(4096 * 8 * 2);
    __half* Wtf1  = (__half*)alloc(2048 * 8 * 2);
    __half* Wtf2  = (__half*)alloc(2048 * 8 * 2);
    float*  Wa0   = (float*)alloc(128 * 8 * 4);
    float*  Wa1   = (float*)alloc(64 * 8 * 4);
    float*  Wa2   = (float*)alloc(64 * 8 * 4);
    int* counts = (int*)alloc((size_t)N_NODES * 4);
    int* indptr = (int*)alloc((size_t)(N_NODES + 1) * 4);
    int* cursor = (int*)alloc((size_t)N_NODES * 4);
    int* esrc   = (int*)alloc((size_t)E_TOT * 4);
    int* edst   = (int*)alloc((size_t)E_TOT * 4);
    int* bsums  = (int*)alloc(256 * 4);
    int* flag   = (int*)alloc(256 * 4);

    // CSR build (graph is identical each call; ws is re-poisoned so rebuild)
    zero_counts<<<NB_SCAN, 256, 0, stream>>>(counts, flag);
    detect_i32<<<1, 256, 0, stream>>>(ei, flag);
    count_edges<<<NB_EDGE, 256, 0, stream>>>(ei, counts, flag);
    scan1<<<NB_SCAN, 256, 0, stream>>>(counts, indptr, bsums);
    scan2<<<1, 256, 0, stream>>>(bsums);
    scan3<<<NB_SCAN, 256, 0, stream>>>(indptr, bsums, cursor);
    fill_edges<<<NB_EDGE, 256, 0, stream>>>(ei, cursor, esrc, edst, flag);

    // weight prep + input cast
    wtf_kernel<<<32, 256, 0, stream>>>(W[0], W[1], W[2], Wtf0, Wtf1, Wtf2);
    wa_kernel<<<256, 256, 0, stream>>>(W[0], W[1], W[2], asrc[0], adst[0],
                                       asrc[1], adst[1], asrc[2], adst[2],
                                       Wa0, Wa1, Wa2);
    cast16<<<6250, 256, 0, stream>>>(x, Xh0, N_NODES * 128 / 4);

    // Layer 0
    gemm_h<128><<<NB_GEMH, 256, 0, stream>>>(Xh0, Wtf0, H);
    al_gemm<128><<<NB_NODE, 256, 0, stream>>>(x, Wa0, AL);
    edge_weights<<<NB_EDGE, 256, 0, stream>>>(AL, esrc, edst, EW);
    aggregate<<<NB_NODE, 256, 0, stream>>>(H, EW, indptr, esrc, bias[0], XA, XA16);
    // Layer 1
    gemm_h<64><<<NB_GEMH, 256, 0, stream>>>(XA16, Wtf1, H);
    al_gemm<64><<<NB_NODE, 256, 0, stream>>>(XA, Wa1, AL);
    edge_weights<<<NB_EDGE, 256, 0, stream>>>(AL, esrc, edst, EW);
    aggregate<<<NB_NODE, 256, 0, stream>>>(H, EW, indptr, esrc, bias[1], XB, XB16);
    // Layer 2
    gemm_h<64><<<NB_GEMH, 256, 0, stream>>>(XB16, Wtf2, H);
    al_gemm<64><<<NB_NODE, 256, 0, stream>>>(XB, Wa2, AL);
    edge_weights<<<NB_EDGE, 256, 0, stream>>>(AL, esrc, edst, EW);
    aggregate<<<NB_NODE, 256, 0, stream>>>(H, EW, indptr, esrc, bias[2], XA, XA16);

    // Final FC
    fc_kernel<<<NB_SCAN, 256, 0, stream>>>(XA, fcW, fcb, out);
}

// Round 15
// 531.005 us; speedup vs baseline: 1.1828x; 1.0823x over previous
//
#include <hip/hip_runtime.h>
#include <hip/hip_fp16.h>
#include <math.h>

// Problem constants (from reference)
#define N_NODES 50000
#define IN_DIM  128
#define HIDDEN  64
#define OUT_DIM 10
#define HEADS   4
#define E_RAW   800000
#define E_TOT   (E_RAW + N_NODES)   // with self-loops: 850000
#define NEG_SLOPE 0.2f

#define NB_SCAN 196    // ceil(50000/256)
#define NB_EDGE 3321   // ceil(850000/256)
#define NB_GEMH 782    // ceil(50000/64)
#define NB_NODE 12500  // 50000/4 (one wave per node)

typedef _Float16 half8 __attribute__((ext_vector_type(8)));
typedef float floatx4 __attribute__((ext_vector_type(4)));

// ---------------- edge_index dtype detection ----------------
// flag[0] == 1  =>  int32 layout (shift 0);  flag[0] == 0  =>  int64 (shift 1).
__global__ void detect_i32(const int* __restrict__ ei, int* __restrict__ flag) {
    int t = threadIdx.x;                      // single block of 256
    int idx = 2 * (t * 3100 + 17) + 1;        // odd, < 1.6M for t < 256
    if (ei[idx] != 0) atomicOr(flag, 1);
}

// ---------------- CSR build ----------------

__global__ void zero_counts(int* __restrict__ counts, int* __restrict__ flag) {
    int i = blockIdx.x * 256 + threadIdx.x;
    if (i < N_NODES) counts[i] = 0;
    if (i == 0) flag[0] = 0;
}

__global__ void count_edges(const int* __restrict__ ei, int* __restrict__ counts,
                            const int* __restrict__ flag) {
    int t = blockIdx.x * 256 + threadIdx.x;
    if (t >= E_TOT) return;
    int sh = flag[0] ? 0 : 1;                 // int32 -> 0, int64 -> 1 (low word)
    int dst = (t < E_RAW) ? ei[(E_RAW + t) << sh] : (t - E_RAW);
    atomicAdd(&counts[dst], 1);
}

__global__ void scan1(const int* __restrict__ counts, int* __restrict__ indptr,
                      int* __restrict__ bsums) {
    __shared__ int sd[256];
    int t = threadIdx.x;
    int i = blockIdx.x * 256 + t;
    int v = (i < N_NODES) ? counts[i] : 0;
    sd[t] = v;
    __syncthreads();
    for (int o = 1; o < 256; o <<= 1) {
        int x = (t >= o) ? sd[t - o] : 0;
        __syncthreads();
        sd[t] += x;
        __syncthreads();
    }
    int incl = sd[t];
    if (i < N_NODES) indptr[i] = incl - v;   // block-local exclusive
    if (t == 255) bsums[blockIdx.x] = incl;  // block total
}

__global__ void scan2(int* __restrict__ bsums) {
    __shared__ int sd[256];
    int t = threadIdx.x;
    int v = (t < NB_SCAN) ? bsums[t] : 0;
    sd[t] = v;
    __syncthreads();
    for (int o = 1; o < 256; o <<= 1) {
        int x = (t >= o) ? sd[t - o] : 0;
        __syncthreads();
        sd[t] += x;
        __syncthreads();
    }
    if (t < NB_SCAN) bsums[t] = sd[t] - v;   // exclusive block offsets
}

__global__ void scan3(int* __restrict__ indptr, const int* __restrict__ bsums,
                      int* __restrict__ cursor) {
    int i = blockIdx.x * 256 + threadIdx.x;
    if (i < N_NODES) {
        int v = indptr[i] + bsums[blockIdx.x];
        indptr[i] = v;
        cursor[i] = v;
    }
    if (i == 0) indptr[N_NODES] = E_TOT;
}

__global__ void fill_edges(const int* __restrict__ ei, int* __restrict__ cursor,
                           int* __restrict__ esrc, int* __restrict__ edst,
                           const int* __restrict__ flag) {
    int t = blockIdx.x * 256 + threadIdx.x;
    if (t >= E_TOT) return;
    int sh = flag[0] ? 0 : 1;
    int src, dst;
    if (t < E_RAW) { src = ei[t << sh]; dst = ei[(E_RAW + t) << sh]; }
    else           { src = t - E_RAW; dst = src; }
    int pos = atomicAdd(&cursor[dst], 1);
    esrc[pos] = src;
    edst[pos] = dst;
}

// ---------------- Weight prep ----------------
// Wtf = fp16 W in MFMA B-FRAGMENT ORDER (verified r13/r14): fragment
// f=(ct,kc,lane) holds 8 halfs W[k=kc*32+quad*8+j][col=ct*16+m].
__global__ void wtf_kernel(const float* __restrict__ W0, const float* __restrict__ W1,
                           const float* __restrict__ W2, __half* __restrict__ Wtf0,
                           __half* __restrict__ Wtf1, __half* __restrict__ Wtf2) {
    int i = blockIdx.x * 256 + threadIdx.x;
    int K, f;
    const float* W; __half* Wtf;
    if (i < 4096)      { f = i;        K = 128; W = W0; Wtf = Wtf0; }
    else if (i < 6144) { f = i - 4096; K = 64;  W = W1; Wtf = Wtf1; }
    else if (i < 8192) { f = i - 6144; K = 64;  W = W2; Wtf = Wtf2; }
    else return;
    int KC = K / 32;
    int lane = f & 63, kc = (f >> 6) % KC, ct = f / (64 * KC);
    int m = lane & 15, quad = lane >> 4;
    int col = ct * 16 + m;
    __half tmp[8];
#pragma unroll
    for (int j = 0; j < 8; j++)
        tmp[j] = __float2half(W[(kc * 32 + quad * 8 + j) * 256 + col]);
    *(uint4*)(Wtf + (size_t)f * 8) = *(uint4*)tmp;
}

// Wa[k][0..7] = f32 (W·asrc | W·adst): exact-f32 logit path (AL = X @ Wa).
__global__ void wa_kernel(const float* __restrict__ W0, const float* __restrict__ W1,
                          const float* __restrict__ W2,
                          const float* __restrict__ as0, const float* __restrict__ ad0,
                          const float* __restrict__ as1, const float* __restrict__ ad1,
                          const float* __restrict__ as2, const float* __restrict__ ad2,
                          float* __restrict__ Wa0, float* __restrict__ Wa1,
                          float* __restrict__ Wa2) {
    int b = blockIdx.x;   // 0..255: L0 k=0..127; L1 k=0..63; L2 k=0..63
    int l, k;
    if (b < 128)      { l = 0; k = b; }
    else if (b < 192) { l = 1; k = b - 128; }
    else              { l = 2; k = b - 192; }
    const float* W  = (l == 0) ? W0 : (l == 1) ? W1 : W2;
    const float* as = (l == 0) ? as0 : (l == 1) ? as1 : as2;
    const float* ad = (l == 0) ? ad0 : (l == 1) ? ad1 : ad2;
    float* Wa       = (l == 0) ? Wa0 : (l == 1) ? Wa1 : Wa2;
    int h = threadIdx.x >> 6, d = threadIdx.x & 63;
    float wv = W[k * 256 + h * 64 + d];
    float ss = wv * as[h * 64 + d];
    float dd = wv * ad[h * 64 + d];
#pragma unroll
    for (int o = 1; o < 64; o <<= 1) {
        ss += __shfl_xor(ss, o, 64);
        dd += __shfl_xor(dd, o, 64);
    }
    if (d == 0) {
        Wa[k * 8 + h]     = ss;
        Wa[k * 8 + 4 + h] = dd;
    }
}

// ---------------- Layer-0 input cast + exact-f32 logits (fused) ------------
// One wave per node: lane owns k=2*lane,2*lane+1. Emits fp16 Xh row AND
// AL[n] = x @ Wa0 (f32, butterfly reduce) in one pass over x.
__global__ void __launch_bounds__(256) cast_al(
    const float* __restrict__ X, const float* __restrict__ Wa,
    __half* __restrict__ Xh, float* __restrict__ AL) {
    __shared__ float waT[8 * 128];   // [j][k]
    int t = threadIdx.x;
    for (int i = t; i < 1024; i += 256) {
        int k = i >> 3, j = i & 7;
        waT[j * 128 + k] = Wa[i];
    }
    __syncthreads();
    int wave = t >> 6, lane = t & 63;
    int n = blockIdx.x * 4 + wave;   // 12500*4 == 50000
    float2 v = ((const float2*)(X + (size_t)n * 128))[lane];
    ((__half2*)(Xh + (size_t)n * 128))[lane] = __float22half2_rn(make_float2(v.x, v.y));
    float s[8];
#pragma unroll
    for (int j = 0; j < 8; j++)
        s[j] = v.x * waT[j * 128 + 2 * lane] + v.y * waT[j * 128 + 2 * lane + 1];
#pragma unroll
    for (int o = 1; o < 64; o <<= 1)
#pragma unroll
        for (int j = 0; j < 8; j++) s[j] += __shfl_xor(s[j], o, 64);
    if (lane == 0) {
        *(float4*)(AL + n * 8)     = make_float4(s[0], s[1], s[2], s[3]);
        *(float4*)(AL + n * 8 + 4) = make_float4(s[4], s[5], s[6], s[7]);
    }
}

// ---------------- H GEMM via MFMA (fp16 in, f32 acc, fp16 out) -------------
// (byte-identical math to r14 — verified absmax 1.22e-4)
template <int K>
__global__ void __launch_bounds__(256) gemm_h(
    const __half* __restrict__ Xh, const __half* __restrict__ Wtf,
    __half* __restrict__ H) {
    __shared__ _Float16 lds[16384];   // 32 KB
    const int KC = K / 32;
    const int CTC = (K == 128) ? 8 : 16;   // ct's per stage chunk
    const int NCHUNK = 16 / CTC;
    int t = threadIdx.x;
    int w = t >> 6, lane = t & 63;
    int m = lane & 15, quad = lane >> 4;
    int n0 = blockIdx.x * 64;
    int nr = n0 + w * 16 + m;
    int nc = (nr < N_NODES) ? nr : (N_NODES - 1);   // clamp; stores guarded

    half8 afrag[KC];
#pragma unroll
    for (int kc = 0; kc < KC; kc++)
        afrag[kc] = *(const half8*)(Xh + (size_t)nc * K + kc * 32 + quad * 8);

    floatx4 accs[16];
    const uint4* Wg = (const uint4*)Wtf;
#pragma unroll
    for (int c = 0; c < NCHUNK; c++) {
        __syncthreads();
        uint4* dstl = (uint4*)lds;
        const uint4* srcg = Wg + (size_t)c * 2048;
#pragma unroll
        for (int q = 0; q < 8; q++) dstl[t + 256 * q] = srcg[t + 256 * q];
        __syncthreads();
#pragma unroll
        for (int ctl = 0; ctl < CTC; ctl++) {
            floatx4 acc = {0.f, 0.f, 0.f, 0.f};
#pragma unroll
            for (int kc = 0; kc < KC; kc++) {
                half8 b = *(const half8*)&lds[((ctl * KC + kc) * 64 + lane) * 8];
                acc = __builtin_amdgcn_mfma_f32_16x16x32_f16(afrag[kc], b, acc, 0, 0, 0);
            }
            accs[c * CTC + ctl] = acc;
        }
    }
    __syncthreads();
    _Float16* myl = lds + w * (16 * 256);
#pragma unroll
    for (int ct = 0; ct < 16; ct++) {
        int cc = ct * 16 + m;          // global col = h*64 + d
        int h = cc >> 6, d = cc & 63;
#pragma unroll
        for (int i = 0; i < 4; i++)
            myl[(quad * 4 + i) * 256 + d * 4 + h] = (_Float16)accs[ct][i];
    }
    __syncthreads();
    int r = t >> 2, p = t & 3;
    int n2 = n0 + r;
    if (n2 < N_NODES) {
        const uint4* src = (const uint4*)(lds + (r >> 4) * (16 * 256) + (r & 15) * 256 + p * 64);
        uint4* dst = (uint4*)(H + (size_t)n2 * 256 + p * 64);
#pragma unroll
        for (int j = 0; j < 8; j++) dst[j] = src[j];
    }
}

// ---------------- Per-edge unnormalized attention weights ----------------
// EW[p] = exp(leaky(AL_src + AL_dst)). No max shift: logits analytically
// bounded (validated rounds 4-14); logit path is exact f32 via Wa.
__global__ void __launch_bounds__(256) edge_weights(
    const float* __restrict__ AL, const int* __restrict__ esrc,
    const int* __restrict__ edst, float4* __restrict__ EW) {
    int p = blockIdx.x * 256 + threadIdx.x;
    if (p >= E_TOT) return;
    int s = esrc[p], d = edst[p];
    const float4* AL4 = (const float4*)AL;
    float4 as = AL4[s * 2];        // src logits (4 heads)
    float4 ad = AL4[d * 2 + 1];    // dst logits (4 heads)
    float v0 = as.x + ad.x; v0 = fmaxf(v0, NEG_SLOPE * v0);
    float v1 = as.y + ad.y; v1 = fmaxf(v1, NEG_SLOPE * v1);
    float v2 = as.z + ad.z; v2 = fmaxf(v2, NEG_SLOPE * v2);
    float v3 = as.w + ad.w; v3 = fmaxf(v3, NEG_SLOPE * v3);
    EW[p] = make_float4(__expf(v0), __expf(v1), __expf(v2), __expf(v3));
}

// ---------------- Per-destination aggregation (+ fused next-layer AL) ------
// One wave per dst node; depth-8 load pipeline (16 loads in flight/wave —
// r14 showed latency-bound: VALU 46%, 3.1 TB/s < the 3.6 demonstrated).
// Epilogue: output r is in registers, so next layer's logits
// AL[n,j] = sum_lane r * WaN[lane,j] cost 8 FMA + butterfly — the whole
// al_gemm kernel (and its X re-read) fused away. WaN/ALout/X16 null for L2.
__global__ void __launch_bounds__(256) aggregate(
    const __half* __restrict__ H, const float4* __restrict__ EW,
    const int* __restrict__ indptr, const int* __restrict__ esrc,
    const float* __restrict__ bias, const float* __restrict__ WaN,
    float* __restrict__ XOUT, __half* __restrict__ XOUT16,
    float* __restrict__ ALout) {
    __shared__ float waT[8 * 64];   // [j][k] for next layer (K=64)
    int t = threadIdx.x;
    if (WaN) {
        for (int i = t; i < 512; i += 256) {
            int k = i >> 3, j = i & 7;
            waT[j * 64 + k] = WaN[i];
        }
    }
    __syncthreads();
    int wave = t >> 6, lane = t & 63;
    int n = blockIdx.x * 4 + wave;   // 12500 * 4 == 50000 exactly

    int start = indptr[n], end = indptr[n + 1];
    const float2* H2 = (const float2*)H;    // 64 float2 per node row

    float d0 = 0.f, d1 = 0.f, d2 = 0.f, d3 = 0.f;
    float a0 = 0.f, a1 = 0.f, a2 = 0.f, a3 = 0.f;

#define EDGE_BODY(E, Hv)                                            \
    {                                                               \
        d0 += E.x; d1 += E.y; d2 += E.z; d3 += E.w;                 \
        float2 c01 = __half22float2(((const __half2*)&Hv)[0]);      \
        float2 c23 = __half22float2(((const __half2*)&Hv)[1]);      \
        a0 += E.x * c01.x; a1 += E.y * c01.y;                       \
        a2 += E.z * c23.x; a3 += E.w * c23.y;                       \
    }

    for (int cb = start; cb < end; cb += 64) {
        int cnt = end - cb; if (cnt > 64) cnt = 64;
        int my_s = (lane < cnt) ? esrc[cb + lane] : 0;
        for (int base = 0; base < cnt; base += 8) {
            int m = cnt - base;   // wave-uniform
            int r1 = (1 < m ? 1 : 0), r2 = (2 < m ? 2 : 0);
            int r3 = (3 < m ? 3 : 0), r4 = (4 < m ? 4 : 0);
            int r5 = (5 < m ? 5 : 0), r6 = (6 < m ? 6 : 0);
            int r7 = (7 < m ? 7 : 0);
            int s0 = __shfl(my_s, base, 64);
            int s1 = __shfl(my_s, base + r1, 64);
            int s2 = __shfl(my_s, base + r2, 64);
            int s3 = __shfl(my_s, base + r3, 64);
            int s4 = __shfl(my_s, base + r4, 64);
            int s5 = __shfl(my_s, base + r5, 64);
            int s6 = __shfl(my_s, base + r6, 64);
            int s7 = __shfl(my_s, base + r7, 64);
            float4 E0 = EW[cb + base];
            float4 E1 = EW[cb + base + r1];
            float4 E2 = EW[cb + base + r2];
            float4 E3 = EW[cb + base + r3];
            float4 E4 = EW[cb + base + r4];
            float4 E5 = EW[cb + base + r5];
            float4 E6 = EW[cb + base + r6];
            float4 E7 = EW[cb + base + r7];
            float2 H0 = H2[(s0 << 6) + lane];
            float2 H1 = H2[(s1 << 6) + lane];
            float2 Hv2 = H2[(s2 << 6) + lane];
            float2 H3 = H2[(s3 << 6) + lane];
            float2 H4 = H2[(s4 << 6) + lane];
            float2 H5 = H2[(s5 << 6) + lane];
            float2 H6 = H2[(s6 << 6) + lane];
            float2 H7 = H2[(s7 << 6) + lane];
            EDGE_BODY(E0, H0);
            if (m > 1) EDGE_BODY(E1, H1);
            if (m > 2) EDGE_BODY(E2, Hv2);
            if (m > 3) EDGE_BODY(E3, H3);
            if (m > 4) EDGE_BODY(E4, H4);
            if (m > 5) EDGE_BODY(E5, H5);
            if (m > 6) EDGE_BODY(E6, H6);
            if (m > 7) EDGE_BODY(E7, H7);
        }
    }
#undef EDGE_BODY

    float r = a0 / d0 + a1 / d1 + a2 / d2 + a3 / d3;
    r = 0.25f * r + bias[lane];
    r = r > 0.f ? r : (__expf(r) - 1.f);   // ELU
    XOUT[n * 64 + lane] = r;
    if (XOUT16) XOUT16[n * 64 + lane] = __float2half(r);

    if (ALout) {   // fused next-layer logits (exact f32, == al_gemm<64>)
        float s[8];
#pragma unroll
        for (int j = 0; j < 8; j++) s[j] = r * waT[j * 64 + lane];
#pragma unroll
        for (int o = 1; o < 64; o <<= 1)
#pragma unroll
            for (int j = 0; j < 8; j++) s[j] += __shfl_xor(s[j], o, 64);
        if (lane == 0) {
            *(float4*)(ALout + n * 8)     = make_float4(s[0], s[1], s[2], s[3]);
            *(float4*)(ALout + n * 8 + 4) = make_float4(s[4], s[5], s[6], s[7]);
        }
    }
}

// ---------------- Final FC ----------------
__global__ void __launch_bounds__(256) fc_kernel(
    const float* __restrict__ X, const float* __restrict__ fcW,
    const float* __restrict__ fcb, float* __restrict__ OUT) {
    __shared__ float ws[64 * 10];
    __shared__ float bs[10];
    int t = threadIdx.x;
    for (int i = t; i < 640; i += 256) ws[i] = fcW[i];   // 640 > blockDim
    if (t < 10) bs[t] = fcb[t];
    __syncthreads();
    int n = blockIdx.x * 256 + t;
    if (n >= N_NODES) return;
    float acc[10];
#pragma unroll
    for (int c = 0; c < 10; c++) acc[c] = bs[c];
    for (int d = 0; d < 64; d++) {
        float x = X[n * 64 + d];
#pragma unroll
        for (int c = 0; c < 10; c++) acc[c] += x * ws[d * 10 + c];
    }
#pragma unroll
    for (int c = 0; c < 10; c++) OUT[n * 10 + c] = acc[c];
}

// ---------------- Launch ----------------
extern "C" void kernel_launch(void* const* d_in, const int* in_sizes, int n_in,
                              void* d_out, int out_size, void* d_ws, size_t ws_size,
                              hipStream_t stream) {
    const float* x     = (const float*)d_in[0];
    const int*   ei    = (const int*)d_in[1];
    const float* W[3]    = {(const float*)d_in[2], (const float*)d_in[6], (const float*)d_in[10]};
    const float* asrc[3] = {(const float*)d_in[3], (const float*)d_in[7], (const float*)d_in[11]};
    const float* adst[3] = {(const float*)d_in[4], (const float*)d_in[8], (const float*)d_in[12]};
    const float* bias[3] = {(const float*)d_in[5], (const float*)d_in[9], (const float*)d_in[13]};
    const float* fcW = (const float*)d_in[14];
    const float* fcb = (const float*)d_in[15];
    float* out = (float*)d_out;

    char* ws = (char*)d_ws;
    size_t off = 0;
    auto alloc = [&](size_t bytes) {
        void* p = ws + off;
        off = (off + bytes + 255) & ~(size_t)255;
        return p;
    };
    __half* H     = (__half*)alloc((size_t)N_NODES * 256 * 2);  // 25.6 MB fp16
    float*  AL    = (float*)alloc((size_t)N_NODES * 8 * 4);     // 1.6 MB
    float4* EW    = (float4*)alloc((size_t)E_TOT * 16);         // 13.6 MB
    float*  XA    = (float*)alloc((size_t)N_NODES * 64 * 4);    // 12.8 MB
    float*  XB    = (float*)alloc((size_t)N_NODES * 64 * 4);    // 12.8 MB
    __half* Xh0   = (__half*)alloc((size_t)N_NODES * 128 * 2);  // 12.8 MB
    __half* XA16  = (__half*)alloc((size_t)N_NODES * 64 * 2);   // 6.4 MB
    __half* XB16  = (__half*)alloc((size_t)N_NODES * 64 * 2);   // 6.4 MB
    __half* Wtf0  = (__half*)alloc(4096 * 8 * 2);
    __half* Wtf1  = (__half*)alloc(2048 * 8 * 2);
    __half* Wtf2  = (__half*)alloc(2048 * 8 * 2);
    float*  Wa0   = (float*)alloc(128 * 8 * 4);
    float*  Wa1   = (float*)alloc(64 * 8 * 4);
    float*  Wa2   = (float*)alloc(64 * 8 * 4);
    int* counts = (int*)alloc((size_t)N_NODES * 4);
    int* indptr = (int*)alloc((size_t)(N_NODES + 1) * 4);
    int* cursor = (int*)alloc((size_t)N_NODES * 4);
    int* esrc   = (int*)alloc((size_t)E_TOT * 4);
    int* edst   = (int*)alloc((size_t)E_TOT * 4);
    int* bsums  = (int*)alloc(256 * 4);
    int* flag   = (int*)alloc(256 * 4);

    // CSR build (graph is identical each call; ws is re-poisoned so rebuild)
    zero_counts<<<NB_SCAN, 256, 0, stream>>>(counts, flag);
    detect_i32<<<1, 256, 0, stream>>>(ei, flag);
    count_edges<<<NB_EDGE, 256, 0, stream>>>(ei, counts, flag);
    scan1<<<NB_SCAN, 256, 0, stream>>>(counts, indptr, bsums);
    scan2<<<1, 256, 0, stream>>>(bsums);
    scan3<<<NB_SCAN, 256, 0, stream>>>(indptr, bsums, cursor);
    fill_edges<<<NB_EDGE, 256, 0, stream>>>(ei, cursor, esrc, edst, flag);

    // weight prep + fused layer-0 cast+logits
    wtf_kernel<<<32, 256, 0, stream>>>(W[0], W[1], W[2], Wtf0, Wtf1, Wtf2);
    wa_kernel<<<256, 256, 0, stream>>>(W[0], W[1], W[2], asrc[0], adst[0],
                                       asrc[1], adst[1], asrc[2], adst[2],
                                       Wa0, Wa1, Wa2);
    cast_al<<<NB_NODE, 256, 0, stream>>>(x, Wa0, Xh0, AL);

    // Layer 0 (aggregate emits AL for layer 1 via Wa1)
    gemm_h<128><<<NB_GEMH, 256, 0, stream>>>(Xh0, Wtf0, H);
    edge_weights<<<NB_EDGE, 256, 0, stream>>>(AL, esrc, edst, EW);
    aggregate<<<NB_NODE, 256, 0, stream>>>(H, EW, indptr, esrc, bias[0], Wa1,
                                           XA, XA16, AL);
    // Layer 1 (aggregate emits AL for layer 2 via Wa2)
    gemm_h<64><<<NB_GEMH, 256, 0, stream>>>(XA16, Wtf1, H);
    edge_weights<<<NB_EDGE, 256, 0, stream>>>(AL, esrc, edst, EW);
    aggregate<<<NB_NODE, 256, 0, stream>>>(H, EW, indptr, esrc, bias[1], Wa2,
                                           XB, XB16, AL);
    // Layer 2 (no next layer: WaN/X16/ALout null)
    gemm_h<64><<<NB_GEMH, 256, 0, stream>>>(XB16, Wtf2, H);
    edge_weights<<<NB_EDGE, 256, 0, stream>>>(AL, esrc, edst, EW);
    aggregate<<<NB_NODE, 256, 0, stream>>>(H, EW, indptr, esrc, bias[2], nullptr,
                                           XA, nullptr, nullptr);

    // Final FC
    fc_kernel<<<NB_SCAN, 256, 0, stream>>>(XA, fcW, fcb, out);
}

// Round 16
// 530.432 us; speedup vs baseline: 1.1841x; 1.0011x over previous
//
#include <hip/hip_runtime.h>
#include <hip/hip_fp16.h>
#include <math.h>

// Problem constants (from reference)
#define N_NODES 50000
#define IN_DIM  128
#define HIDDEN  64
#define OUT_DIM 10
#define HEADS   4
#define E_RAW   800000
#define E_TOT   (E_RAW + N_NODES)   // with self-loops: 850000
#define NEG_SLOPE 0.2f

#define NB_SCAN 196    // ceil(50000/256)
#define NB_EDGE 3321   // ceil(850000/256)
#define NB_GEMH 782    // ceil(50000/64)
#define NB_NODE 12500  // 50000/4 (one wave per node)

typedef _Float16 half8 __attribute__((ext_vector_type(8)));
typedef float floatx4 __attribute__((ext_vector_type(4)));

// ---------------- edge_index dtype detection ----------------
// flag[0] == 1  =>  int32 layout (shift 0);  flag[0] == 0  =>  int64 (shift 1).
__global__ void detect_i32(const int* __restrict__ ei, int* __restrict__ flag) {
    int t = threadIdx.x;                      // single block of 256
    int idx = 2 * (t * 3100 + 17) + 1;        // odd, < 1.6M for t < 256
    if (ei[idx] != 0) atomicOr(flag, 1);
}

// ---------------- CSR build ----------------

__global__ void zero_counts(int* __restrict__ counts, int* __restrict__ flag) {
    int i = blockIdx.x * 256 + threadIdx.x;
    if (i < N_NODES) counts[i] = 0;
    if (i == 0) flag[0] = 0;
}

__global__ void count_edges(const int* __restrict__ ei, int* __restrict__ counts,
                            const int* __restrict__ flag) {
    int t = blockIdx.x * 256 + threadIdx.x;
    if (t >= E_TOT) return;
    int sh = flag[0] ? 0 : 1;                 // int32 -> 0, int64 -> 1 (low word)
    int dst = (t < E_RAW) ? ei[(E_RAW + t) << sh] : (t - E_RAW);
    atomicAdd(&counts[dst], 1);
}

__global__ void scan1(const int* __restrict__ counts, int* __restrict__ indptr,
                      int* __restrict__ bsums) {
    __shared__ int sd[256];
    int t = threadIdx.x;
    int i = blockIdx.x * 256 + t;
    int v = (i < N_NODES) ? counts[i] : 0;
    sd[t] = v;
    __syncthreads();
    for (int o = 1; o < 256; o <<= 1) {
        int x = (t >= o) ? sd[t - o] : 0;
        __syncthreads();
        sd[t] += x;
        __syncthreads();
    }
    int incl = sd[t];
    if (i < N_NODES) indptr[i] = incl - v;   // block-local exclusive
    if (t == 255) bsums[blockIdx.x] = incl;  // block total
}

__global__ void scan2(int* __restrict__ bsums) {
    __shared__ int sd[256];
    int t = threadIdx.x;
    int v = (t < NB_SCAN) ? bsums[t] : 0;
    sd[t] = v;
    __syncthreads();
    for (int o = 1; o < 256; o <<= 1) {
        int x = (t >= o) ? sd[t - o] : 0;
        __syncthreads();
        sd[t] += x;
        __syncthreads();
    }
    if (t < NB_SCAN) bsums[t] = sd[t] - v;   // exclusive block offsets
}

__global__ void scan3(int* __restrict__ indptr, const int* __restrict__ bsums,
                      int* __restrict__ cursor) {
    int i = blockIdx.x * 256 + threadIdx.x;
    if (i < N_NODES) {
        int v = indptr[i] + bsums[blockIdx.x];
        indptr[i] = v;
        cursor[i] = v;
    }
    if (i == 0) indptr[N_NODES] = E_TOT;
}

__global__ void fill_edges(const int* __restrict__ ei, int* __restrict__ cursor,
                           int* __restrict__ esrc, int* __restrict__ edst,
                           const int* __restrict__ flag) {
    int t = blockIdx.x * 256 + threadIdx.x;
    if (t >= E_TOT) return;
    int sh = flag[0] ? 0 : 1;
    int src, dst;
    if (t < E_RAW) { src = ei[t << sh]; dst = ei[(E_RAW + t) << sh]; }
    else           { src = t - E_RAW; dst = src; }
    int pos = atomicAdd(&cursor[dst], 1);
    esrc[pos] = src;
    edst[pos] = dst;
}

// ---------------- Weight prep ----------------
// Wtf = fp16 W in MFMA B-FRAGMENT ORDER (verified r13/r14): fragment
// f=(ct,kc,lane) holds 8 halfs W[k=kc*32+quad*8+j][col=ct*16+m].
__global__ void wtf_kernel(const float* __restrict__ W0, const float* __restrict__ W1,
                           const float* __restrict__ W2, __half* __restrict__ Wtf0,
                           __half* __restrict__ Wtf1, __half* __restrict__ Wtf2) {
    int i = blockIdx.x * 256 + threadIdx.x;
    int K, f;
    const float* W; __half* Wtf;
    if (i < 4096)      { f = i;        K = 128; W = W0; Wtf = Wtf0; }
    else if (i < 6144) { f = i - 4096; K = 64;  W = W1; Wtf = Wtf1; }
    else if (i < 8192) { f = i - 6144; K = 64;  W = W2; Wtf = Wtf2; }
    else return;
    int KC = K / 32;
    int lane = f & 63, kc = (f >> 6) % KC, ct = f / (64 * KC);
    int m = lane & 15, quad = lane >> 4;
    int col = ct * 16 + m;
    __half tmp[8];
#pragma unroll
    for (int j = 0; j < 8; j++)
        tmp[j] = __float2half(W[(kc * 32 + quad * 8 + j) * 256 + col]);
    *(uint4*)(Wtf + (size_t)f * 8) = *(uint4*)tmp;
}

// Wa[k][0..7] = f32 (W·asrc | W·adst): exact-f32 logit path (AL = X @ Wa).
__global__ void wa_kernel(const float* __restrict__ W0, const float* __restrict__ W1,
                          const float* __restrict__ W2,
                          const float* __restrict__ as0, const float* __restrict__ ad0,
                          const float* __restrict__ as1, const float* __restrict__ ad1,
                          const float* __restrict__ as2, const float* __restrict__ ad2,
                          float* __restrict__ Wa0, float* __restrict__ Wa1,
                          float* __restrict__ Wa2) {
    int b = blockIdx.x;   // 0..255: L0 k=0..127; L1 k=0..63; L2 k=0..63
    int l, k;
    if (b < 128)      { l = 0; k = b; }
    else if (b < 192) { l = 1; k = b - 128; }
    else              { l = 2; k = b - 192; }
    const float* W  = (l == 0) ? W0 : (l == 1) ? W1 : W2;
    const float* as = (l == 0) ? as0 : (l == 1) ? as1 : as2;
    const float* ad = (l == 0) ? ad0 : (l == 1) ? ad1 : ad2;
    float* Wa       = (l == 0) ? Wa0 : (l == 1) ? Wa1 : Wa2;
    int h = threadIdx.x >> 6, d = threadIdx.x & 63;
    float wv = W[k * 256 + h * 64 + d];
    float ss = wv * as[h * 64 + d];
    float dd = wv * ad[h * 64 + d];
#pragma unroll
    for (int o = 1; o < 64; o <<= 1) {
        ss += __shfl_xor(ss, o, 64);
        dd += __shfl_xor(dd, o, 64);
    }
    if (d == 0) {
        Wa[k * 8 + h]     = ss;
        Wa[k * 8 + 4 + h] = dd;
    }
}

// ---------------- Layer-0 input cast + exact-f32 logits (fused) ------------
// One wave per node: lane owns k=2*lane,2*lane+1. Emits fp16 Xh row AND
// AL[n] = x @ Wa0 (f32, butterfly reduce) in one pass over x.
__global__ void __launch_bounds__(256) cast_al(
    const float* __restrict__ X, const float* __restrict__ Wa,
    __half* __restrict__ Xh, float* __restrict__ AL) {
    __shared__ float waT[8 * 128];   // [j][k]
    int t = threadIdx.x;
    for (int i = t; i < 1024; i += 256) {
        int k = i >> 3, j = i & 7;
        waT[j * 128 + k] = Wa[i];
    }
    __syncthreads();
    int wave = t >> 6, lane = t & 63;
    int n = blockIdx.x * 4 + wave;   // 12500*4 == 50000
    float2 v = ((const float2*)(X + (size_t)n * 128))[lane];
    ((__half2*)(Xh + (size_t)n * 128))[lane] = __float22half2_rn(make_float2(v.x, v.y));
    float s[8];
#pragma unroll
    for (int j = 0; j < 8; j++)
        s[j] = v.x * waT[j * 128 + 2 * lane] + v.y * waT[j * 128 + 2 * lane + 1];
#pragma unroll
    for (int o = 1; o < 64; o <<= 1)
#pragma unroll
        for (int j = 0; j < 8; j++) s[j] += __shfl_xor(s[j], o, 64);
    if (lane == 0) {
        *(float4*)(AL + n * 8)     = make_float4(s[0], s[1], s[2], s[3]);
        *(float4*)(AL + n * 8 + 4) = make_float4(s[4], s[5], s[6], s[7]);
    }
}

// ---------------- H GEMM via MFMA (fp16 in, f32 acc, fp16 out) -------------
// (byte-identical math to r14 — verified absmax 1.22e-4)
template <int K>
__global__ void __launch_bounds__(256) gemm_h(
    const __half* __restrict__ Xh, const __half* __restrict__ Wtf,
    __half* __restrict__ H) {
    __shared__ _Float16 lds[16384];   // 32 KB
    const int KC = K / 32;
    const int CTC = (K == 128) ? 8 : 16;   // ct's per stage chunk
    const int NCHUNK = 16 / CTC;
    int t = threadIdx.x;
    int w = t >> 6, lane = t & 63;
    int m = lane & 15, quad = lane >> 4;
    int n0 = blockIdx.x * 64;
    int nr = n0 + w * 16 + m;
    int nc = (nr < N_NODES) ? nr : (N_NODES - 1);   // clamp; stores guarded

    half8 afrag[KC];
#pragma unroll
    for (int kc = 0; kc < KC; kc++)
        afrag[kc] = *(const half8*)(Xh + (size_t)nc * K + kc * 32 + quad * 8);

    floatx4 accs[16];
    const uint4* Wg = (const uint4*)Wtf;
#pragma unroll
    for (int c = 0; c < NCHUNK; c++) {
        __syncthreads();
        uint4* dstl = (uint4*)lds;
        const uint4* srcg = Wg + (size_t)c * 2048;
#pragma unroll
        for (int q = 0; q < 8; q++) dstl[t + 256 * q] = srcg[t + 256 * q];
        __syncthreads();
#pragma unroll
        for (int ctl = 0; ctl < CTC; ctl++) {
            floatx4 acc = {0.f, 0.f, 0.f, 0.f};
#pragma unroll
            for (int kc = 0; kc < KC; kc++) {
                half8 b = *(const half8*)&lds[((ctl * KC + kc) * 64 + lane) * 8];
                acc = __builtin_amdgcn_mfma_f32_16x16x32_f16(afrag[kc], b, acc, 0, 0, 0);
            }
            accs[c * CTC + ctl] = acc;
        }
    }
    __syncthreads();
    _Float16* myl = lds + w * (16 * 256);
#pragma unroll
    for (int ct = 0; ct < 16; ct++) {
        int cc = ct * 16 + m;          // global col = h*64 + d
        int h = cc >> 6, d = cc & 63;
#pragma unroll
        for (int i = 0; i < 4; i++)
            myl[(quad * 4 + i) * 256 + d * 4 + h] = (_Float16)accs[ct][i];
    }
    __syncthreads();
    int r = t >> 2, p = t & 3;
    int n2 = n0 + r;
    if (n2 < N_NODES) {
        const uint4* src = (const uint4*)(lds + (r >> 4) * (16 * 256) + (r & 15) * 256 + p * 64);
        uint4* dst = (uint4*)(H + (size_t)n2 * 256 + p * 64);
#pragma unroll
        for (int j = 0; j < 8; j++) dst[j] = src[j];
    }
}

// ---------------- Per-edge unnormalized attention weights ----------------
// EW[p] = exp(leaky(AL_src + AL_dst)). No max shift: logits analytically
// bounded (validated rounds 4-15); logit path is exact f32 via Wa.
__global__ void __launch_bounds__(256) edge_weights(
    const float* __restrict__ AL, const int* __restrict__ esrc,
    const int* __restrict__ edst, float4* __restrict__ EW) {
    int p = blockIdx.x * 256 + threadIdx.x;
    if (p >= E_TOT) return;
    int s = esrc[p], d = edst[p];
    const float4* AL4 = (const float4*)AL;
    float4 as = AL4[s * 2];        // src logits (4 heads)
    float4 ad = AL4[d * 2 + 1];    // dst logits (4 heads)
    float v0 = as.x + ad.x; v0 = fmaxf(v0, NEG_SLOPE * v0);
    float v1 = as.y + ad.y; v1 = fmaxf(v1, NEG_SLOPE * v1);
    float v2 = as.z + ad.z; v2 = fmaxf(v2, NEG_SLOPE * v2);
    float v3 = as.w + ad.w; v3 = fmaxf(v3, NEG_SLOPE * v3);
    EW[p] = make_float4(__expf(v0), __expf(v1), __expf(v2), __expf(v3));
}

// ---------------- Per-destination aggregation (+ fused next-layer AL) ------
// One wave per dst node; depth-4 load pipeline (r14's proven body: VGPR 28,
// occupancy ~70% — r15's depth-8 cost 12 VGPRs -> occ 54% -> NET LOSS,
// 69->85 us; reverted). Fused epilogue: next layer's logits
// AL[n,j] = sum_lane r * WaN[lane,j] (8 FMA + butterfly; kills al_gemm and
// its X re-read). waT staged with LINEAR writes (r15 wrote stride-64-dword:
// all-bank-0, 1.4M conflict cycles).
__global__ void __launch_bounds__(256) aggregate(
    const __half* __restrict__ H, const float4* __restrict__ EW,
    const int* __restrict__ indptr, const int* __restrict__ esrc,
    const float* __restrict__ bias, const float* __restrict__ WaN,
    float* __restrict__ XOUT, __half* __restrict__ XOUT16,
    float* __restrict__ ALout) {
    __shared__ float waT[8 * 64];   // [j][k] for next layer (K=64)
    int t = threadIdx.x;
    if (WaN) {
        for (int i = t; i < 512; i += 256) {
            int k = i & 63, j = i >> 6;        // addr j*64+k == i: linear
            waT[i] = WaN[k * 8 + j];
        }
    }
    __syncthreads();
    int wave = t >> 6, lane = t & 63;
    int n = blockIdx.x * 4 + wave;   // 12500 * 4 == 50000 exactly

    int start = indptr[n], end = indptr[n + 1];
    const float2* H2 = (const float2*)H;    // 64 float2 per node row

    float d0 = 0.f, d1 = 0.f, d2 = 0.f, d3 = 0.f;
    float a0 = 0.f, a1 = 0.f, a2 = 0.f, a3 = 0.f;

#define EDGE_BODY(E, Hv)                                            \
    {                                                               \
        d0 += E.x; d1 += E.y; d2 += E.z; d3 += E.w;                 \
        float2 c01 = __half22float2(((const __half2*)&Hv)[0]);      \
        float2 c23 = __half22float2(((const __half2*)&Hv)[1]);      \
        a0 += E.x * c01.x; a1 += E.y * c01.y;                       \
        a2 += E.z * c23.x; a3 += E.w * c23.y;                       \
    }

    for (int cb = start; cb < end; cb += 64) {
        int cnt = end - cb; if (cnt > 64) cnt = 64;
        int my_s = (lane < cnt) ? esrc[cb + lane] : 0;
        for (int base = 0; base < cnt; base += 4) {
            int m = cnt - base;   // wave-uniform
            int r1 = (1 < m ? 1 : 0), r2 = (2 < m ? 2 : 0), r3 = (3 < m ? 3 : 0);
            int s0 = __shfl(my_s, base, 64);
            int s1 = __shfl(my_s, base + r1, 64);
            int s2 = __shfl(my_s, base + r2, 64);
            int s3 = __shfl(my_s, base + r3, 64);
            float4 E0 = EW[cb + base];                       // uniform -> bcast
            float4 E1 = EW[cb + base + r1];
            float4 E2 = EW[cb + base + r2];
            float4 E3 = EW[cb + base + r3];
            float2 H0 = H2[(s0 << 6) + lane];
            float2 H1 = H2[(s1 << 6) + lane];
            float2 H2v = H2[(s2 << 6) + lane];
            float2 H3 = H2[(s3 << 6) + lane];
            EDGE_BODY(E0, H0);
            if (m > 1) EDGE_BODY(E1, H1);
            if (m > 2) EDGE_BODY(E2, H2v);
            if (m > 3) EDGE_BODY(E3, H3);
        }
    }
#undef EDGE_BODY

    float r = a0 / d0 + a1 / d1 + a2 / d2 + a3 / d3;
    r = 0.25f * r + bias[lane];
    r = r > 0.f ? r : (__expf(r) - 1.f);   // ELU
    XOUT[n * 64 + lane] = r;
    if (XOUT16) XOUT16[n * 64 + lane] = __float2half(r);

    if (ALout) {   // fused next-layer logits (exact f32, == al_gemm<64>)
        float s[8];
#pragma unroll
        for (int j = 0; j < 8; j++) s[j] = r * waT[j * 64 + lane];
#pragma unroll
        for (int o = 1; o < 64; o <<= 1)
#pragma unroll
            for (int j = 0; j < 8; j++) s[j] += __shfl_xor(s[j], o, 64);
        if (lane == 0) {
            *(float4*)(ALout + n * 8)     = make_float4(s[0], s[1], s[2], s[3]);
            *(float4*)(ALout + n * 8 + 4) = make_float4(s[4], s[5], s[6], s[7]);
        }
    }
}

// ---------------- Final FC ----------------
__global__ void __launch_bounds__(256) fc_kernel(
    const float* __restrict__ X, const float* __restrict__ fcW,
    const float* __restrict__ fcb, float* __restrict__ OUT) {
    __shared__ float ws[64 * 10];
    __shared__ float bs[10];
    int t = threadIdx.x;
    for (int i = t; i < 640; i += 256) ws[i] = fcW[i];   // 640 > blockDim
    if (t < 10) bs[t] = fcb[t];
    __syncthreads();
    int n = blockIdx.x * 256 + t;
    if (n >= N_NODES) return;
    float acc[10];
#pragma unroll
    for (int c = 0; c < 10; c++) acc[c] = bs[c];
    for (int d = 0; d < 64; d++) {
        float x = X[n * 64 + d];
#pragma unroll
        for (int c = 0; c < 10; c++) acc[c] += x * ws[d * 10 + c];
    }
#pragma unroll
    for (int c = 0; c < 10; c++) OUT[n * 10 + c] = acc[c];
}

// ---------------- Launch ----------------
extern "C" void kernel_launch(void* const* d_in, const int* in_sizes, int n_in,
                              void* d_out, int out_size, void* d_ws, size_t ws_size,
                              hipStream_t stream) {
    const float* x     = (const float*)d_in[0];
    const int*   ei    = (const int*)d_in[1];
    const float* W[3]    = {(const float*)d_in[2], (const float*)d_in[6], (const float*)d_in[10]};
    const float* asrc[3] = {(const float*)d_in[3], (const float*)d_in[7], (const float*)d_in[11]};
    const float* adst[3] = {(const float*)d_in[4], (const float*)d_in[8], (const float*)d_in[12]};
    const float* bias[3] = {(const float*)d_in[5], (const float*)d_in[9], (const float*)d_in[13]};
    const float* fcW = (const float*)d_in[14];
    const float* fcb = (const float*)d_in[15];
    float* out = (float*)d_out;

    char* ws = (char*)d_ws;
    size_t off = 0;
    auto alloc = [&](size_t bytes) {
        void* p = ws + off;
        off = (off + bytes + 255) & ~(size_t)255;
        return p;
    };
    __half* H     = (__half*)alloc((size_t)N_NODES * 256 * 2);  // 25.6 MB fp16
    float*  AL    = (float*)alloc((size_t)N_NODES * 8 * 4);     // 1.6 MB
    float4* EW    = (float4*)alloc((size_t)E_TOT * 16);         // 13.6 MB
    float*  XA    = (float*)alloc((size_t)N_NODES * 64 * 4);    // 12.8 MB
    float*  XB    = (float*)alloc((size_t)N_NODES * 64 * 4);    // 12.8 MB
    __half* Xh0   = (__half*)alloc((size_t)N_NODES * 128 * 2);  // 12.8 MB
    __half* XA16  = (__half*)alloc((size_t)N_NODES * 64 * 2);   // 6.4 MB
    __half* XB16  = (__half*)alloc((size_t)N_NODES * 64 * 2);   // 6.4 MB
    __half* Wtf0  = (__half*)alloc(4096 * 8 * 2);
    __half* Wtf1  = (__half*)alloc(2048 * 8 * 2);
    __half* Wtf2  = (__half*)alloc(2048 * 8 * 2);
    float*  Wa0   = (float*)alloc(128 * 8 * 4);
    float*  Wa1   = (float*)alloc(64 * 8 * 4);
    float*  Wa2   = (float*)alloc(64 * 8 * 4);
    int* counts = (int*)alloc((size_t)N_NODES * 4);
    int* indptr = (int*)alloc((size_t)(N_NODES + 1) * 4);
    int* cursor = (int*)alloc((size_t)N_NODES * 4);
    int* esrc   = (int*)alloc((size_t)E_TOT * 4);
    int* edst   = (int*)alloc((size_t)E_TOT * 4);
    int* bsums  = (int*)alloc(256 * 4);
    int* flag   = (int*)alloc(256 * 4);

    // CSR build (graph is identical each call; ws is re-poisoned so rebuild)
    zero_counts<<<NB_SCAN, 256, 0, stream>>>(counts, flag);
    detect_i32<<<1, 256, 0, stream>>>(ei, flag);
    count_edges<<<NB_EDGE, 256, 0, stream>>>(ei, counts, flag);
    scan1<<<NB_SCAN, 256, 0, stream>>>(counts, indptr, bsums);
    scan2<<<1, 256, 0, stream>>>(bsums);
    scan3<<<NB_SCAN, 256, 0, stream>>>(indptr, bsums, cursor);
    fill_edges<<<NB_EDGE, 256, 0, stream>>>(ei, cursor, esrc, edst, flag);

    // weight prep + fused layer-0 cast+logits
    wtf_kernel<<<32, 256, 0, stream>>>(W[0], W[1], W[2], Wtf0, Wtf1, Wtf2);
    wa_kernel<<<256, 256, 0, stream>>>(W[0], W[1], W[2], asrc[0], adst[0],
                                       asrc[1], adst[1], asrc[2], adst[2],
                                       Wa0, Wa1, Wa2);
    cast_al<<<NB_NODE, 256, 0, stream>>>(x, Wa0, Xh0, AL);

    // Layer 0 (aggregate emits AL for layer 1 via Wa1)
    gemm_h<128><<<NB_GEMH, 256, 0, stream>>>(Xh0, Wtf0, H);
    edge_weights<<<NB_EDGE, 256, 0, stream>>>(AL, esrc, edst, EW);
    aggregate<<<NB_NODE, 256, 0, stream>>>(H, EW, indptr, esrc, bias[0], Wa1,
                                           XA, XA16, AL);
    // Layer 1 (aggregate emits AL for layer 2 via Wa2)
    gemm_h<64><<<NB_GEMH, 256, 0, stream>>>(XA16, Wtf1, H);
    edge_weights<<<NB_EDGE, 256, 0, stream>>>(AL, esrc, edst, EW);
    aggregate<<<NB_NODE, 256, 0, stream>>>(H, EW, indptr, esrc, bias[1], Wa2,
                                           XB, XB16, AL);
    // Layer 2 (no next layer: WaN/X16/ALout null)
    gemm_h<64><<<NB_GEMH, 256, 0, stream>>>(XB16, Wtf2, H);
    edge_weights<<<NB_EDGE, 256, 0, stream>>>(AL, esrc, edst, EW);
    aggregate<<<NB_NODE, 256, 0, stream>>>(H, EW, indptr, esrc, bias[2], nullptr,
                                           XA, nullptr, nullptr);

    // Final FC
    fc_kernel<<<NB_SCAN, 256, 0, stream>>>(XA, fcW, fcb, out);
}